// Round 4
// baseline (368.692 us; speedup 1.0000x reference)
//
#include <hip/hip_runtime.h>
#include <hip/hip_cooperative_groups.h>
#include <math.h>

namespace cg = cooperative_groups;

typedef _Float16 half_t;
typedef _Float16 half8  __attribute__((ext_vector_type(8)));
typedef _Float16 half4v __attribute__((ext_vector_type(4)));
typedef float    floatx4 __attribute__((ext_vector_type(4)));

#define LOG2E 1.44269504088896f

static __device__ __forceinline__ floatx4 mfma16(half8 a, half8 b, floatx4 c) {
    return __builtin_amdgcn_mfma_f32_16x16x32_f16(a, b, c, 0, 0, 0);
}
static __device__ __forceinline__ floatx4 mfma16x16(half4v a, half4v b, floatx4 c) {
    return __builtin_amdgcn_mfma_f32_16x16x16f16(a, b, c, 0, 0, 0);
}

// ---------------------------------------------------------------------------
// proj_core: 512-thr 64x64-tile GEMM, K=1024 split into two 4-wave halves
// (BK=64 x 8 iters, double-buffered, register prefetch), fp32 LDS merge.
// task 0: q-proj. task 1: k/v-proj (+transpose epilogues). task 2: out-proj.
// Uses 73728 B LDS at sm.
// ---------------------------------------------------------------------------
static __device__ __forceinline__ void proj_core(int task, int m0, int n0,
                                                 const float* __restrict__ Af,
                                                 const half_t* __restrict__ Ah,
                                                 const half_t* __restrict__ Bt,
                                                 half_t* __restrict__ qs_h,
                                                 half_t* __restrict__ kp_h,
                                                 half_t* __restrict__ Vp4,
                                                 float* __restrict__ out,
                                                 float* __restrict__ out_k,
                                                 float* __restrict__ out_v,
                                                 half_t* sm, int tid)
{
    half_t* As = sm;                 // [kh][buf][64*72]
    half_t* Bs = sm + 4 * 4608;

    const int kh = tid >> 8, t8 = tid & 255;
    const int w4 = (tid >> 6) & 3, l = tid & 63;
    const int quad = l >> 4, lr = l & 15, wm = w4 >> 1, wn = w4 & 1;
    const int arow = t8 >> 2, acol = (t8 & 3) * 16;
    const int kbase = kh * 512;
    half_t* Ak = As + kh * 2 * 4608;
    half_t* Bk = Bs + kh * 2 * 4608;

    {   // stage tile 0
        int kk = kbase;
        if (Af) {
            float4 f0 = *(const float4*)&Af[(size_t)(m0 + arow) * 1024 + kk + acol];
            float4 f1 = *(const float4*)&Af[(size_t)(m0 + arow) * 1024 + kk + acol + 4];
            float4 f2 = *(const float4*)&Af[(size_t)(m0 + arow) * 1024 + kk + acol + 8];
            float4 f3 = *(const float4*)&Af[(size_t)(m0 + arow) * 1024 + kk + acol + 12];
            half8 h0, h1;
            h0[0]=(half_t)f0.x; h0[1]=(half_t)f0.y; h0[2]=(half_t)f0.z; h0[3]=(half_t)f0.w;
            h0[4]=(half_t)f1.x; h0[5]=(half_t)f1.y; h0[6]=(half_t)f1.z; h0[7]=(half_t)f1.w;
            h1[0]=(half_t)f2.x; h1[1]=(half_t)f2.y; h1[2]=(half_t)f2.z; h1[3]=(half_t)f2.w;
            h1[4]=(half_t)f3.x; h1[5]=(half_t)f3.y; h1[6]=(half_t)f3.z; h1[7]=(half_t)f3.w;
            *(half8*)&Ak[arow * 72 + acol] = h0;
            *(half8*)&Ak[arow * 72 + acol + 8] = h1;
        } else {
            *(half8*)&Ak[arow * 72 + acol]     = *(const half8*)&Ah[(size_t)(m0 + arow) * 1024 + kk + acol];
            *(half8*)&Ak[arow * 72 + acol + 8] = *(const half8*)&Ah[(size_t)(m0 + arow) * 1024 + kk + acol + 8];
        }
        *(half8*)&Bk[arow * 72 + acol]     = *(const half8*)&Bt[(size_t)(n0 + arow) * 1024 + kk + acol];
        *(half8*)&Bk[arow * 72 + acol + 8] = *(const half8*)&Bt[(size_t)(n0 + arow) * 1024 + kk + acol + 8];
    }
    __syncthreads();

    floatx4 zero = {0.f, 0.f, 0.f, 0.f};
    floatx4 acc[2][2];
    acc[0][0] = zero; acc[0][1] = zero; acc[1][0] = zero; acc[1][1] = zero;

    float4 pf0, pf1, pf2, pf3; half8 ph0, ph1, pb0, pb1;
    for (int it = 0; it < 8; ++it) {
        if (it < 7) {
            int kk = kbase + (it + 1) * 64;
            if (Af) {
                pf0 = *(const float4*)&Af[(size_t)(m0 + arow) * 1024 + kk + acol];
                pf1 = *(const float4*)&Af[(size_t)(m0 + arow) * 1024 + kk + acol + 4];
                pf2 = *(const float4*)&Af[(size_t)(m0 + arow) * 1024 + kk + acol + 8];
                pf3 = *(const float4*)&Af[(size_t)(m0 + arow) * 1024 + kk + acol + 12];
            } else {
                ph0 = *(const half8*)&Ah[(size_t)(m0 + arow) * 1024 + kk + acol];
                ph1 = *(const half8*)&Ah[(size_t)(m0 + arow) * 1024 + kk + acol + 8];
            }
            pb0 = *(const half8*)&Bt[(size_t)(n0 + arow) * 1024 + kk + acol];
            pb1 = *(const half8*)&Bt[(size_t)(n0 + arow) * 1024 + kk + acol + 8];
        }
        const half_t* Ab = Ak + (it & 1) * 4608;
        const half_t* Bb = Bk + (it & 1) * 4608;
        #pragma unroll
        for (int ks = 0; ks < 2; ++ks) {
            half8 a0 = *(const half8*)&Ab[(wm * 32 + lr) * 72 + ks * 32 + quad * 8];
            half8 a1 = *(const half8*)&Ab[(wm * 32 + 16 + lr) * 72 + ks * 32 + quad * 8];
            half8 b0 = *(const half8*)&Bb[(wn * 32 + lr) * 72 + ks * 32 + quad * 8];
            half8 b1 = *(const half8*)&Bb[(wn * 32 + 16 + lr) * 72 + ks * 32 + quad * 8];
            acc[0][0] = mfma16(a0, b0, acc[0][0]);
            acc[0][1] = mfma16(a0, b1, acc[0][1]);
            acc[1][0] = mfma16(a1, b0, acc[1][0]);
            acc[1][1] = mfma16(a1, b1, acc[1][1]);
        }
        __syncthreads();
        if (it < 7) {
            int buf = (it + 1) & 1;
            if (Af) {
                half8 h0, h1;
                h0[0]=(half_t)pf0.x; h0[1]=(half_t)pf0.y; h0[2]=(half_t)pf0.z; h0[3]=(half_t)pf0.w;
                h0[4]=(half_t)pf1.x; h0[5]=(half_t)pf1.y; h0[6]=(half_t)pf1.z; h0[7]=(half_t)pf1.w;
                h1[0]=(half_t)pf2.x; h1[1]=(half_t)pf2.y; h1[2]=(half_t)pf2.z; h1[3]=(half_t)pf2.w;
                h1[4]=(half_t)pf3.x; h1[5]=(half_t)pf3.y; h1[6]=(half_t)pf3.z; h1[7]=(half_t)pf3.w;
                *(half8*)&Ak[buf * 4608 + arow * 72 + acol] = h0;
                *(half8*)&Ak[buf * 4608 + arow * 72 + acol + 8] = h1;
            } else {
                *(half8*)&Ak[buf * 4608 + arow * 72 + acol] = ph0;
                *(half8*)&Ak[buf * 4608 + arow * 72 + acol + 8] = ph1;
            }
            *(half8*)&Bk[buf * 4608 + arow * 72 + acol] = pb0;
            *(half8*)&Bk[buf * 4608 + arow * 72 + acol + 8] = pb1;
            __syncthreads();
        }
    }

    // merge K-halves (kh1 -> LDS fp32, kh0 adds)
    float* M = (float*)Bs;   // 64 x 66 floats
    if (kh == 1) {
        #pragma unroll
        for (int mi = 0; mi < 2; mi++)
            #pragma unroll
            for (int ni = 0; ni < 2; ni++)
                #pragma unroll
                for (int r = 0; r < 4; r++)
                    M[(wm * 32 + mi * 16 + quad * 4 + r) * 66 + wn * 32 + ni * 16 + lr] = acc[mi][ni][r];
    }
    __syncthreads();
    if (kh == 0) {
        #pragma unroll
        for (int mi = 0; mi < 2; mi++)
            #pragma unroll
            for (int ni = 0; ni < 2; ni++)
                #pragma unroll
                for (int r = 0; r < 4; r++)
                    acc[mi][ni][r] += M[(wm * 32 + mi * 16 + quad * 4 + r) * 66 + wn * 32 + ni * 16 + lr];
    }

    if (task == 0) {
        if (kh == 0) {
            #pragma unroll
            for (int mi = 0; mi < 2; mi++)
                #pragma unroll
                for (int ni = 0; ni < 2; ni++)
                    #pragma unroll
                    for (int r = 0; r < 4; r++) {
                        int m = m0 + wm * 32 + mi * 16 + quad * 4 + r;
                        int n = n0 + wn * 32 + ni * 16 + lr;
                        qs_h[(size_t)m * 1024 + n] = (half_t)(acc[mi][ni][r] * (0.125f * LOG2E));
                    }
        }
    } else if (task == 2) {
        if (kh == 0) {
            #pragma unroll
            for (int mi = 0; mi < 2; mi++)
                #pragma unroll
                for (int ni = 0; ni < 2; ni++)
                    #pragma unroll
                    for (int r = 0; r < 4; r++) {
                        int m = m0 + wm * 32 + mi * 16 + quad * 4 + r;
                        int n = n0 + wn * 32 + ni * 16 + lr;
                        out[(size_t)m * 1024 + n] = acc[mi][ni][r];
                    }
        }
    } else {
        float* Ct = (float*)As;   // 64 x 68 floats (transposed acc)
        if (kh == 0) {
            #pragma unroll
            for (int mi = 0; mi < 2; mi++)
                #pragma unroll
                for (int ni = 0; ni < 2; ni++)
                    #pragma unroll
                    for (int r = 0; r < 4; r++)
                        Ct[(wn * 32 + ni * 16 + lr) * 68 + wm * 32 + mi * 16 + quad * 4 + r] = acc[mi][ni][r];
        }
        __syncthreads();
        if (kh == 0) {
            const int b = m0 >> 9, jm0 = m0 & 511;
            if (n0 < 256) {
                int gg = n0 >> 6;
                {
                    int d = t8 >> 2, jc = (t8 & 3) * 16;
                    float4 vv[4];
                    #pragma unroll
                    for (int u = 0; u < 4; u++) vv[u] = *(float4*)&Ct[d * 68 + jc + u * 4];
                    #pragma unroll
                    for (int t = 0; t < 4; t++)
                        #pragma unroll
                        for (int u = 0; u < 4; u++)
                            *(float4*)&out_k[((size_t)((b * 16 + gg * 4 + t) * 64 + d)) * 1536 + 1024 + jm0 + jc + u * 4] = vv[u];
                }
                {
                    int j = t8 >> 2, dc = (t8 & 3) * 16;
                    half8 o0, o1;
                    #pragma unroll
                    for (int u = 0; u < 8; u++) o0[u] = (half_t)Ct[(dc + u) * 68 + j];
                    #pragma unroll
                    for (int u = 0; u < 8; u++) o1[u] = (half_t)Ct[(dc + 8 + u) * 68 + j];
                    *(half8*)&kp_h[((size_t)(b * 512 + jm0 + j)) * 256 + n0 + dc] = o0;
                    *(half8*)&kp_h[((size_t)(b * 512 + jm0 + j)) * 256 + n0 + dc + 8] = o1;
                }
            } else {
                int gg = (n0 - 256) >> 6;
                {
                    int j = t8 >> 2, dc = (t8 & 3) * 16;
                    float4 vv[4];
                    #pragma unroll
                    for (int u = 0; u < 4; u++) {
                        float4 x;
                        x.x = Ct[(dc + u * 4 + 0) * 68 + j];
                        x.y = Ct[(dc + u * 4 + 1) * 68 + j];
                        x.z = Ct[(dc + u * 4 + 2) * 68 + j];
                        x.w = Ct[(dc + u * 4 + 3) * 68 + j];
                        vv[u] = x;
                    }
                    #pragma unroll
                    for (int t = 0; t < 4; t++)
                        #pragma unroll
                        for (int u = 0; u < 4; u++)
                            *(float4*)&out_v[(((size_t)(b * 16 + gg * 4 + t) * 1536) + 1024 + jm0 + j) * 64 + dc + u * 4] = vv[u];
                }
                {   // Vp4[(b*4+gg)][jc'][d][4]
                    int d = t8 >> 2, jc16 = (t8 & 3) * 16;
                    #pragma unroll
                    for (int u = 0; u < 4; u++) {
                        half4v o;
                        #pragma unroll
                        for (int s2 = 0; s2 < 4; s2++) o[s2] = (half_t)Ct[d * 68 + jc16 + u * 4 + s2];
                        *(half4v*)&Vp4[(((size_t)(b * 4 + gg) * 128 + ((jm0 + jc16) >> 2) + u) * 64 + d) * 4] = o;
                    }
                }
            }
        }
    }
}

// ---------------------------------------------------------------------------
// Phase A body: all transposes. 2256 units of 256-thr work, 2 units/block
// (sub = tid>>8), 5 rounds over 256 blocks.
// units: [0,768) cache_k->Kc + out_k shift; [768,1536) cache_v->Vc4 + out_v
// shift; [1536,2176) weight transposes; [2176,2256) embc build.
// ---------------------------------------------------------------------------
static __device__ __forceinline__ void phaseA_body(int bid, int tid,
    const float* __restrict__ cache_k, const float* __restrict__ cache_v,
    const float* __restrict__ Wq, const float* __restrict__ Wk,
    const float* __restrict__ Wv, const float* __restrict__ Wo,
    const float* __restrict__ emb_t, const float* __restrict__ emb_f,
    half_t* __restrict__ Kc, half_t* __restrict__ Vc4,
    float* __restrict__ out_k, float* __restrict__ out_v,
    half_t* __restrict__ WqT, half_t* __restrict__ WkvT,
    half_t* __restrict__ WoT, half_t* __restrict__ embc,
    unsigned char* sm)
{
    const int sub = tid >> 8, tl = tid & 255;
    float (*t)[65] = (float(*)[65])(sm + sub * 16640);
    #pragma unroll 1
    for (int r = 0; r < 5; ++r) {
        const int u = r * 512 + bid * 2 + sub;
        int cat = -1, p0 = 0, p1 = 0;
        if (u < 768)       { cat = 0; p0 = u % 24; p1 = u / 24; }
        else if (u < 1536) { cat = 1; int u2 = u - 768; p0 = u2 % 24; p1 = u2 / 24; }
        else if (u < 2176) { cat = 2; p0 = u - 1536; }
        else if (u < 2256) { cat = 3; p0 = u - 2176; }
        const float* wsrc = nullptr; half_t* wdst = nullptr; int Ncols = 0, n0 = 0, k0 = 0;
        if (cat == 2) {
            int w = p0;
            if (w < 256)      { wsrc = Wq; wdst = WqT; Ncols = 1024; n0 = (w & 15) * 64; k0 = (w >> 4) * 64; }
            else if (w < 320) { int q2 = w - 256; wsrc = Wk; wdst = WkvT; Ncols = 256; n0 = (q2 & 3) * 64; k0 = (q2 >> 2) * 64; }
            else if (w < 384) { int q2 = w - 320; wsrc = Wv; wdst = WkvT + 256 * 1024; Ncols = 256; n0 = (q2 & 3) * 64; k0 = (q2 >> 2) * 64; }
            else              { int q2 = w - 384; wsrc = Wo; wdst = WoT; Ncols = 1024; n0 = (q2 & 15) * 64; k0 = (q2 >> 4) * 64; }
        }
        // ---- LOAD stage ----
        if (cat == 0) {
            const int bh = p1, j0 = p0 * 64;
            const bool shift = (j0 >= 512);
            #pragma unroll
            for (int i2 = 0; i2 < 4; i2++) {
                int idx = i2 * 256 + tl;
                int d = idx >> 4, j4 = (idx & 15) * 4;
                float4 vv = *(const float4*)&cache_k[((size_t)bh * 64 + d) * 1536 + j0 + j4];
                *(float4*)&t[d][j4] = vv;
                if (shift) *(float4*)&out_k[((size_t)bh * 64 + d) * 1536 + j0 - 512 + j4] = vv;
            }
        } else if (cat == 1) {
            const int bh = p1, j0 = p0 * 64;
            const bool shift = (j0 >= 512);
            #pragma unroll
            for (int i2 = 0; i2 < 4; i2++) {
                int idx = i2 * 256 + tl;
                int j = idx >> 4, d4 = (idx & 15) * 4;
                float4 vv = *(const float4*)&cache_v[((size_t)bh * 1536 + j0 + j) * 64 + d4];
                *(float4*)&t[j][d4] = vv;
                if (shift) *(float4*)&out_v[((size_t)bh * 1536 + j0 + j - 512) * 64 + d4] = vv;
            }
        } else if (cat == 2) {
            #pragma unroll
            for (int i2 = 0; i2 < 4; i2++) {
                int idx = i2 * 256 + tl;
                int rr = idx >> 4, c4 = (idx & 15) * 4;
                *(float4*)&t[rr][c4] = *(const float4*)&wsrc[(size_t)(k0 + rr) * Ncols + n0 + c4];
            }
        } else if (cat == 3) {
            int idx = p0 * 256 + tl;
            int row = idx >> 6, col = idx & 63;
            float val = 0.f;
            if (row < 255) val = emb_t[row * 64 + col];
            else if (row >= 256 && row < 271) val = emb_f[(row - 256) * 64 + col];
            embc[idx] = (half_t)val;
        }
        __syncthreads();
        // ---- STORE stage ----
        if (cat == 0) {
            const int bh = p1, j0 = p0 * 64;
            #pragma unroll
            for (int i2 = 0; i2 < 2; i2++) {
                int idx = i2 * 256 + tl;
                int j = idx >> 3, db = (idx & 7) * 8;
                half8 o;
                #pragma unroll
                for (int uu = 0; uu < 8; uu++) o[uu] = (half_t)t[db + uu][j];
                *(half8*)&Kc[((size_t)bh * 1536 + j0 + j) * 64 + db] = o;
            }
        } else if (cat == 1) {
            const int bh = p1, j0 = p0 * 64;
            #pragma unroll
            for (int i2 = 0; i2 < 4; i2++) {
                int idx = i2 * 256 + tl;
                int jc = idx >> 6, d = idx & 63;
                half4v o;
                #pragma unroll
                for (int uu = 0; uu < 4; uu++) o[uu] = (half_t)t[jc * 4 + uu][d];
                *(half4v*)&Vc4[(((size_t)bh * 384 + (j0 >> 2) + jc) * 64 + d) * 4] = o;
            }
        } else if (cat == 2) {
            #pragma unroll
            for (int i2 = 0; i2 < 2; i2++) {
                int idx = i2 * 256 + tl;
                int n = idx >> 3, kb = (idx & 7) * 8;
                half8 o;
                #pragma unroll
                for (int uu = 0; uu < 8; uu++) o[uu] = (half_t)t[kb + uu][n];
                *(half8*)&wdst[(size_t)(n0 + n) * 1024 + k0 + kb] = o;
            }
        }
        __syncthreads();
    }
}

// ---------------------------------------------------------------------------
// flash_core (v7): barrier-free main loop, K and V prefetched one iter ahead
// in registers. 8 waves; wave jh owns 16 j-rows of each 128-j tile, all 32 i.
// Needs 61824 B LDS. Caller must barrier before entry (LDS reuse).
// ---------------------------------------------------------------------------
static __device__ __forceinline__ void flash_core(int bh, int i0,
    const half_t* __restrict__ qs_h, const half_t* __restrict__ Kc,
    const half_t* __restrict__ kp_h, const half_t* __restrict__ Vc4,
    const half_t* __restrict__ Vp4, const half_t* __restrict__ embc,
    half_t* __restrict__ AO, unsigned char* smem_raw, int tid)
{
    half_t* bt = (half_t*)smem_raw;              // [32][210]
    const int b = bh >> 4, h = bh & 15, g = h >> 2;
    const int jh = tid >> 6, l = tid & 63;
    const int quad = l >> 4, lr = l & 15;

    half8 qf[2][2];
    #pragma unroll
    for (int ih = 0; ih < 2; ih++) {
        const half_t* qsrc = &qs_h[((size_t)(b * 512 + i0 + ih * 16 + lr)) * 1024 + h * 64];
        qf[ih][0] = *(const half8*)(qsrc + quad * 8);
        qf[ih][1] = *(const half8*)(qsrc + 32 + quad * 8);
    }

    floatx4 zero = {0.f, 0.f, 0.f, 0.f};
    {   // bias GEMM: bt[i][t-64] = q_i . embc[t]
        int ih = jh & 1;
        for (int tk = 4 + (jh >> 1); tk < 17; tk += 4) {
            floatx4 acc = zero;
            half8 e0 = *(const half8*)&embc[(size_t)(tk * 16 + lr) * 64 + quad * 8];
            half8 e1 = *(const half8*)&embc[(size_t)(tk * 16 + lr) * 64 + 32 + quad * 8];
            acc = mfma16(e0, qf[ih][0], acc);
            acc = mfma16(e1, qf[ih][1], acc);
            #pragma unroll
            for (int r = 0; r < 4; r++)
                bt[(ih * 16 + lr) * 210 + tk * 16 + quad * 4 + r - 64] = (half_t)acc[r];
        }
    }
    __syncthreads();   // bt ready

    float bfv[2][4];
    #pragma unroll
    for (int ih = 0; ih < 2; ih++)
        #pragma unroll
        for (int r = 0; r < 4; r++) {
            int f = (lr & 7) - ((quad & 1) * 4 + r) + 7;
            bfv[ih][r] = (float)bt[(ih * 16 + lr) * 210 + 192 + f];
        }
    const int qtr0 = (i0 + lr) >> 3;
    const int qtr1 = (i0 + 16 + lr) >> 3;

    floatx4 accO[2][4];
    #pragma unroll
    for (int ih = 0; ih < 2; ih++)
        #pragma unroll
        for (int ni = 0; ni < 4; ni++) accO[ih][ni] = zero;
    floatx4 accS[2];
    accS[0] = zero; accS[1] = zero;
    const half4v vone = {(half_t)1.f, (half_t)1.f, (half_t)1.f, (half_t)1.f};

    half8 kc0, kc1; half4v vb[4];
    {
        const half_t* kb = &Kc[((size_t)bh * 1536 + jh * 16 + lr) * 64];
        kc0 = *(const half8*)(kb + quad * 8);
        kc1 = *(const half8*)(kb + 32 + quad * 8);
        const half_t* vbase = Vc4 + (size_t)bh * 98304;
        const int jc = jh * 4 + quad;
        #pragma unroll
        for (int ni = 0; ni < 4; ni++)
            vb[ni] = *(const half4v*)&vbase[((size_t)jc * 64 + ni * 16 + lr) * 4];
    }

    for (int jt = 0; jt < 16; ++jt) {
        half8 kn0, kn1; half4v vn[4];
        if (jt < 15) {
            const int j1 = (jt + 1) * 128;
            const half_t* kb = (j1 < 1536)
                ? &Kc[((size_t)bh * 1536 + j1 + jh * 16 + lr) * 64]
                : &kp_h[((size_t)(b * 512 + j1 - 1536 + jh * 16 + lr)) * 256 + g * 64];
            kn0 = *(const half8*)(kb + quad * 8);
            kn1 = *(const half8*)(kb + 32 + quad * 8);
            const half_t* vbase; int jcb;
            if (j1 < 1536) { vbase = Vc4 + (size_t)bh * 98304;          jcb = j1 >> 2; }
            else           { vbase = Vp4 + (size_t)(b * 4 + g) * 32768; jcb = (j1 - 1536) >> 2; }
            const int jc = jcb + jh * 4 + quad;
            #pragma unroll
            for (int ni = 0; ni < 4; ni++)
                vn[ni] = *(const half4v*)&vbase[((size_t)jc * 64 + ni * 16 + lr) * 4];
        }

        floatx4 s[2];
        #pragma unroll
        for (int ih = 0; ih < 2; ih++) {
            s[ih] = mfma16(kc0, qf[ih][0], zero);
            s[ih] = mfma16(kc1, qf[ih][1], s[ih]);
        }
        const int ktb = jt * 16 + jh * 2 + (quad >> 1);
        #pragma unroll
        for (int ih = 0; ih < 2; ih++) {
            int toff = 255 + (ih ? qtr1 : qtr0) - ktb;
            toff = min(toff, 190);
            float tb = (float)bt[(ih * 16 + lr) * 210 + toff];
            #pragma unroll
            for (int r = 0; r < 4; r++)
                s[ih][r] = exp2f(s[ih][r] + tb + bfv[ih][r]);
        }
        #pragma unroll
        for (int ih = 0; ih < 2; ih++) {
            half4v pf;
            #pragma unroll
            for (int r = 0; r < 4; r++) pf[r] = (half_t)s[ih][r];
            accS[ih] = mfma16x16(pf, vone, accS[ih]);
            #pragma unroll
            for (int ni = 0; ni < 4; ni++)
                accO[ih][ni] = mfma16x16(pf, vb[ni], accO[ih][ni]);
        }
        if (jt < 15) {
            kc0 = kn0; kc1 = kn1;
            #pragma unroll
            for (int ni = 0; ni < 4; ni++) vb[ni] = vn[ni];
        }
    }

    __syncthreads();
    float* Mf = (float*)smem_raw;          // 7 partials x 32 x 68 fp32
    float* Sf = Mf + 7 * 32 * 68;          // 7 x 32 fp32
    if (jh != 0) {
        const int p = jh - 1;
        #pragma unroll
        for (int ih = 0; ih < 2; ih++) {
            #pragma unroll
            for (int ni = 0; ni < 4; ni++)
                #pragma unroll
                for (int r = 0; r < 4; r++)
                    Mf[(p * 32 + ih * 16 + quad * 4 + r) * 68 + ni * 16 + lr] = accO[ih][ni][r];
            if (lr == 0) {
                #pragma unroll
                for (int r = 0; r < 4; r++)
                    Sf[p * 32 + ih * 16 + quad * 4 + r] = accS[ih][r];
            }
        }
    }
    __syncthreads();
    if (jh == 0) {
        #pragma unroll
        for (int ih = 0; ih < 2; ih++) {
            float inv[4];
            #pragma unroll
            for (int r = 0; r < 4; r++) {
                float tt = accS[ih][r];
                #pragma unroll
                for (int p = 0; p < 7; p++) tt += Sf[p * 32 + ih * 16 + quad * 4 + r];
                inv[r] = 1.0f / tt;
            }
            #pragma unroll
            for (int ni = 0; ni < 4; ni++)
                #pragma unroll
                for (int r = 0; r < 4; r++) {
                    float o = accO[ih][ni][r];
                    #pragma unroll
                    for (int p = 0; p < 7; p++)
                        o += Mf[(p * 32 + ih * 16 + quad * 4 + r) * 68 + ni * 16 + lr];
                    int row = ih * 16 + quad * 4 + r;
                    AO[((size_t)(b * 512 + i0 + row)) * 1024 + h * 64 + ni * 16 + lr] =
                        (half_t)(o * inv[r]);
                }
        }
    }
}

static __device__ __forceinline__ void phaseB_body(int bid, int tid,
    const float* qin, const float* kin, const float* vin,
    const half_t* WqT, const half_t* WkvT,
    half_t* qs_h, half_t* kp_h, half_t* Vp4,
    float* out_k, float* out_v, unsigned char* sm)
{
    #pragma unroll 1
    for (int t2 = bid; t2 < 384; t2 += 256) {
        int task, m0, n0;
        const float* Af; const half_t* Bt;
        if (t2 < 256) { task = 0; m0 = (t2 >> 4) * 64; n0 = (t2 & 15) * 64; Af = qin; Bt = WqT; }
        else { task = 1; int t3 = t2 - 256; m0 = (t3 >> 3) * 64; n0 = (t3 & 7) * 64;
               Af = (n0 < 256) ? kin : vin; Bt = WkvT; }
        __syncthreads();
        proj_core(task, m0, n0, Af, nullptr, Bt, qs_h, kp_h, Vp4,
                  nullptr, out_k, out_v, (half_t*)sm, tid);
    }
}

static __device__ __forceinline__ void phaseC_body(int bid, int tid,
    const half_t* qs_h, const half_t* Kc, const half_t* kp_h,
    const half_t* Vc4, const half_t* Vp4, const half_t* embc,
    half_t* AO, unsigned char* sm)
{
    #pragma unroll 1
    for (int u = bid; u < 512; u += 256) {
        __syncthreads();
        flash_core(u & 31, (u >> 5) * 32, qs_h, Kc, kp_h, Vc4, Vp4, embc, AO, sm, tid);
    }
}

// ---------------------------------------------------------------------------
// fused: ONE cooperative kernel, 256 blocks x 512 thr, grid.sync() between
// phases: A transposes -> B q/k/v proj -> C flash -> D out-proj.
// ---------------------------------------------------------------------------
__global__ __launch_bounds__(512, 2) void fused(
    const float* __restrict__ qin, const float* __restrict__ kin,
    const float* __restrict__ vin, const float* __restrict__ cache_k,
    const float* __restrict__ cache_v, const float* __restrict__ Wq,
    const float* __restrict__ Wk, const float* __restrict__ Wv,
    const float* __restrict__ Wo, const float* __restrict__ emb_t,
    const float* __restrict__ emb_f,
    float* __restrict__ out, float* __restrict__ out_k, float* __restrict__ out_v,
    half_t* __restrict__ qs_h, half_t* __restrict__ kp_h, half_t* __restrict__ Vp4,
    half_t* __restrict__ Kc, half_t* __restrict__ Vc4,
    half_t* __restrict__ WqT, half_t* __restrict__ WkvT, half_t* __restrict__ WoT,
    half_t* __restrict__ embc, half_t* __restrict__ AO)
{
    __shared__ __align__(16) unsigned char sm[73728];
    cg::grid_group grid = cg::this_grid();
    const int bid = blockIdx.x, tid = threadIdx.x;

    phaseA_body(bid, tid, cache_k, cache_v, Wq, Wk, Wv, Wo, emb_t, emb_f,
                Kc, Vc4, out_k, out_v, WqT, WkvT, WoT, embc, sm);
    grid.sync();
    phaseB_body(bid, tid, qin, kin, vin, WqT, WkvT, qs_h, kp_h, Vp4,
                out_k, out_v, sm);
    grid.sync();
    phaseC_body(bid, tid, qs_h, Kc, kp_h, Vc4, Vp4, embc, AO, sm);
    grid.sync();
    if (bid < 256)
        proj_core(2, (bid >> 4) * 64, (bid & 15) * 64, nullptr, AO, WoT,
                  nullptr, nullptr, nullptr, out, nullptr, nullptr,
                  (half_t*)sm, tid);
}

// ----- non-cooperative fallback wrappers (same bodies, 4 launches) ---------
__global__ __launch_bounds__(512, 2) void k_phaseA(
    const float* cache_k, const float* cache_v, const float* Wq,
    const float* Wk, const float* Wv, const float* Wo,
    const float* emb_t, const float* emb_f,
    half_t* Kc, half_t* Vc4, float* out_k, float* out_v,
    half_t* WqT, half_t* WkvT, half_t* WoT, half_t* embc)
{
    __shared__ __align__(16) unsigned char sm[73728];
    phaseA_body(blockIdx.x, threadIdx.x, cache_k, cache_v, Wq, Wk, Wv, Wo,
                emb_t, emb_f, Kc, Vc4, out_k, out_v, WqT, WkvT, WoT, embc, sm);
}
__global__ __launch_bounds__(512, 2) void k_phaseB(
    const float* qin, const float* kin, const float* vin,
    const half_t* WqT, const half_t* WkvT,
    half_t* qs_h, half_t* kp_h, half_t* Vp4, float* out_k, float* out_v)
{
    __shared__ __align__(16) unsigned char sm[73728];
    phaseB_body(blockIdx.x, threadIdx.x, qin, kin, vin, WqT, WkvT,
                qs_h, kp_h, Vp4, out_k, out_v, sm);
}
__global__ __launch_bounds__(512, 2) void k_phaseC(
    const half_t* qs_h, const half_t* Kc, const half_t* kp_h,
    const half_t* Vc4, const half_t* Vp4, const half_t* embc, half_t* AO)
{
    __shared__ __align__(16) unsigned char sm[73728];
    phaseC_body(blockIdx.x, threadIdx.x, qs_h, Kc, kp_h, Vc4, Vp4, embc, AO, sm);
}
__global__ __launch_bounds__(512, 2) void k_phaseD(
    const half_t* AO, const half_t* WoT, float* out)
{
    __shared__ __align__(16) unsigned char sm[73728];
    proj_core(2, (blockIdx.x >> 4) * 64, (blockIdx.x & 15) * 64, nullptr, AO,
              WoT, nullptr, nullptr, nullptr, out, nullptr, nullptr,
              (half_t*)sm, threadIdx.x);
}

// ---------------------------------------------------------------------------
extern "C" void kernel_launch(void* const* d_in, const int* in_sizes, int n_in,
                              void* d_out, int out_size, void* d_ws, size_t ws_size,
                              hipStream_t stream)
{
    const float* qin     = (const float*)d_in[0];
    const float* kin     = (const float*)d_in[1];
    const float* vin     = (const float*)d_in[2];
    const float* cache_k = (const float*)d_in[3];
    const float* cache_v = (const float*)d_in[4];
    const float* Wq      = (const float*)d_in[5];
    const float* Wk      = (const float*)d_in[6];
    const float* Wv      = (const float*)d_in[7];
    const float* Wo      = (const float*)d_in[8];
    const float* emb_t   = (const float*)d_in[9];
    const float* emb_f   = (const float*)d_in[10];

    float* out   = (float*)d_out;                 // (2,512,1024)
    float* out_k = out + 1048576;                 // (32,64,1536)
    float* out_v = out_k + 3145728;               // (32,1536,64)

    half_t* ws = (half_t*)d_ws;
    half_t* qs_h = ws;                  // 1048576
    half_t* kp_h = ws + 1048576;        //  262144
    half_t* Vp4  = ws + 1310720;        //  262144
    half_t* Kc   = ws + 1572864;        // 3145728
    half_t* Vc4  = ws + 4718592;        // 3145728
    half_t* WqT  = ws + 7864320;        // 1048576
    half_t* WkvT = ws + 8912896;        //  524288
    half_t* WoT  = ws + 9437184;        // 1048576
    half_t* embc = ws + 10485760;       //   20480
    half_t* AO   = ws + 10506240;       // 1048576

    void* args[] = {
        (void*)&qin, (void*)&kin, (void*)&vin, (void*)&cache_k, (void*)&cache_v,
        (void*)&Wq, (void*)&Wk, (void*)&Wv, (void*)&Wo, (void*)&emb_t, (void*)&emb_f,
        (void*)&out, (void*)&out_k, (void*)&out_v,
        (void*)&qs_h, (void*)&kp_h, (void*)&Vp4, (void*)&Kc, (void*)&Vc4,
        (void*)&WqT, (void*)&WkvT, (void*)&WoT, (void*)&embc, (void*)&AO
    };
    hipError_t e = hipLaunchCooperativeKernel((const void*)fused, dim3(256),
                                              dim3(512), args, 0, stream);
    if (e != hipSuccess) {
        (void)hipGetLastError();
        k_phaseA<<<dim3(256), 512, 0, stream>>>(cache_k, cache_v, Wq, Wk, Wv, Wo,
                                                emb_t, emb_f, Kc, Vc4, out_k, out_v,
                                                WqT, WkvT, WoT, embc);
        k_phaseB<<<dim3(256), 512, 0, stream>>>(qin, kin, vin, WqT, WkvT,
                                                qs_h, kp_h, Vp4, out_k, out_v);
        k_phaseC<<<dim3(256), 512, 0, stream>>>(qs_h, Kc, kp_h, Vc4, Vp4, embc, AO);
        k_phaseD<<<dim3(256), 512, 0, stream>>>(AO, WoT, out);
    }
}

// Round 6
// 174.086 us; speedup vs baseline: 2.1179x; 2.1179x over previous
//
#include <hip/hip_runtime.h>
#include <math.h>

typedef _Float16 half_t;
typedef _Float16 half8  __attribute__((ext_vector_type(8)));
typedef _Float16 half4v __attribute__((ext_vector_type(4)));
typedef float    floatx4 __attribute__((ext_vector_type(4)));

#define LOG2E 1.44269504088896f

static __device__ __forceinline__ floatx4 mfma16(half8 a, half8 b, floatx4 c) {
    return __builtin_amdgcn_mfma_f32_16x16x32_f16(a, b, c, 0, 0, 0);
}
static __device__ __forceinline__ floatx4 mfma16x16(half4v a, half4v b, floatx4 c) {
    return __builtin_amdgcn_mfma_f32_16x16x16f16(a, b, c, 0, 0, 0);
}

// ---------------------------------------------------------------------------
// prep (256 thr): z=0 cache_k -> Kc[bh][j][d] fp16 + out_k shift fp32
//                 z=1 cache_v -> Vc4[bh][j/4][d][4] fp16 + out_v shift fp32
//                 z=2 weight transposes + embc build. All float4 loads.
// ---------------------------------------------------------------------------
__global__ __launch_bounds__(256) void prep(const float* __restrict__ cache_k,
                                            const float* __restrict__ cache_v,
                                            const float* __restrict__ Wq,
                                            const float* __restrict__ Wk,
                                            const float* __restrict__ Wv,
                                            const float* __restrict__ Wo,
                                            const float* __restrict__ emb_t,
                                            const float* __restrict__ emb_f,
                                            half_t* __restrict__ Kc,
                                            half_t* __restrict__ Vc4,
                                            float* __restrict__ out_k,
                                            float* __restrict__ out_v,
                                            half_t* __restrict__ WqT,
                                            half_t* __restrict__ WkvT,
                                            half_t* __restrict__ WoT,
                                            half_t* __restrict__ embc)
{
    const int tid = threadIdx.x;
    const int z = blockIdx.z;
    __shared__ float t[64][65];
    if (z == 0) {
        const int bh = blockIdx.y, j0 = blockIdx.x * 64;
        const bool shift = (j0 >= 512);
        #pragma unroll
        for (int i2 = 0; i2 < 4; i2++) {
            int idx = i2 * 256 + tid;
            int d = idx >> 4, j4 = (idx & 15) * 4;
            float4 vv = *(const float4*)&cache_k[((size_t)bh * 64 + d) * 1536 + j0 + j4];
            *(float4*)&t[d][j4] = vv;
            if (shift) *(float4*)&out_k[((size_t)bh * 64 + d) * 1536 + j0 - 512 + j4] = vv;
        }
        __syncthreads();
        #pragma unroll
        for (int i2 = 0; i2 < 2; i2++) {
            int idx = i2 * 256 + tid;
            int j = idx >> 3, db = (idx & 7) * 8;
            half8 o;
            #pragma unroll
            for (int u = 0; u < 8; u++) o[u] = (half_t)t[db + u][j];
            *(half8*)&Kc[((size_t)bh * 1536 + j0 + j) * 64 + db] = o;
        }
    } else if (z == 1) {
        const int bh = blockIdx.y, j0 = blockIdx.x * 64;
        const bool shift = (j0 >= 512);
        #pragma unroll
        for (int i2 = 0; i2 < 4; i2++) {
            int idx = i2 * 256 + tid;
            int j = idx >> 4, d4 = (idx & 15) * 4;
            float4 vv = *(const float4*)&cache_v[((size_t)bh * 1536 + j0 + j) * 64 + d4];
            *(float4*)&t[j][d4] = vv;
            if (shift) *(float4*)&out_v[((size_t)bh * 1536 + j0 + j - 512) * 64 + d4] = vv;
        }
        __syncthreads();
        // Vc4[bh][jc][d][4]: half4 per (jc,d), d fastest over threads (coalesced)
        #pragma unroll
        for (int i2 = 0; i2 < 4; i2++) {
            int idx = i2 * 256 + tid;            // 0..1023
            int jc = idx >> 6, d = idx & 63;     // jc 0..15 local
            half4v o;
            #pragma unroll
            for (int u = 0; u < 4; u++) o[u] = (half_t)t[jc * 4 + u][d];
            *(half4v*)&Vc4[(((size_t)bh * 384 + (j0 >> 2) + jc) * 64 + d) * 4] = o;
        }
    } else {
        const int id = blockIdx.y * 24 + blockIdx.x;
        const float* src; half_t* dst; int Ncols, n0, k0;
        if (id < 256)      { src = Wq; dst = WqT; Ncols = 1024; n0 = (id & 15) * 64; k0 = (id >> 4) * 64; }
        else if (id < 320) { int q2 = id - 256; src = Wk; dst = WkvT; Ncols = 256; n0 = (q2 & 3) * 64; k0 = (q2 >> 2) * 64; }
        else if (id < 384) { int q2 = id - 320; src = Wv; dst = WkvT + 256 * 1024; Ncols = 256; n0 = (q2 & 3) * 64; k0 = (q2 >> 2) * 64; }
        else if (id < 640) { int q2 = id - 384; src = Wo; dst = WoT; Ncols = 1024; n0 = (q2 & 15) * 64; k0 = (q2 >> 4) * 64; }
        else if (id < 720) {
            int idx = (id - 640) * 256 + tid;
            int row = idx >> 6, col = idx & 63;
            float val = 0.f;
            if (row < 255) val = emb_t[row * 64 + col];
            else if (row >= 256 && row < 271) val = emb_f[(row - 256) * 64 + col];
            embc[idx] = (half_t)val;
            return;
        } else return;
        #pragma unroll
        for (int i2 = 0; i2 < 4; i2++) {
            int idx = i2 * 256 + tid;
            int r = idx >> 4, c4 = (idx & 15) * 4;
            *(float4*)&t[r][c4] = *(const float4*)&src[(size_t)(k0 + r) * Ncols + n0 + c4];
        }
        __syncthreads();
        #pragma unroll
        for (int i2 = 0; i2 < 2; i2++) {
            int idx = i2 * 256 + tid;
            int n = idx >> 3, kb = (idx & 7) * 8;
            half8 o;
            #pragma unroll
            for (int u = 0; u < 8; u++) o[u] = (half_t)t[kb + u][n];
            *(half8*)&dst[(size_t)(n0 + n) * 1024 + k0 + kb] = o;
        }
    }
}

// ---------------------------------------------------------------------------
// proj (512 thr, 8 waves, K-split): two 4-wave groups each GEMM half of K
// (BK=64 x 8 iters, double-buffered, register prefetch), fp32 LDS merge.
// phase 0: blocks 0..255 q-proj (fp16, x0.125*log2e), 256..383 k/v-proj
// (LDS-transpose epilogue; V written j-chunked Vp4). phase 1: out-proj.
// ---------------------------------------------------------------------------
__global__ __launch_bounds__(512) void proj(int phase,
                                            const float* __restrict__ qin,
                                            const float* __restrict__ kin,
                                            const float* __restrict__ vin,
                                            const half_t* __restrict__ AO,
                                            const half_t* __restrict__ WqT,
                                            const half_t* __restrict__ WkvT,
                                            const half_t* __restrict__ WoT,
                                            half_t* __restrict__ qs_h,
                                            half_t* __restrict__ kp_h,
                                            half_t* __restrict__ Vp4,
                                            float* __restrict__ out,
                                            float* __restrict__ out_k,
                                            float* __restrict__ out_v)
{
    __shared__ __align__(16) half_t As[2][2][64 * 72];
    __shared__ __align__(16) half_t Bs[2][2][64 * 72];
    const int id = blockIdx.x;
    int task, m0, n0;
    const float* Af = nullptr; const half_t* Ah = nullptr; const half_t* Bt;
    if (phase == 1)      { task = 2; m0 = (id >> 4) * 64; n0 = (id & 15) * 64; Ah = AO; Bt = WoT; }
    else if (id < 256)   { task = 0; m0 = (id >> 4) * 64; n0 = (id & 15) * 64; Af = qin; Bt = WqT; }
    else { task = 1; int t = id - 256; m0 = (t >> 3) * 64; n0 = (t & 7) * 64;
           Af = (n0 < 256) ? kin : vin; Bt = WkvT; }

    const int tid = threadIdx.x;
    const int kh = tid >> 8, t8 = tid & 255;
    const int w4 = (tid >> 6) & 3, l = tid & 63;
    const int quad = l >> 4, lr = l & 15, wm = w4 >> 1, wn = w4 & 1;
    const int arow = t8 >> 2, acol = (t8 & 3) * 16;
    const int kbase = kh * 512;

    {   // stage tile 0
        int kk = kbase;
        if (Af) {
            float4 f0 = *(const float4*)&Af[(size_t)(m0 + arow) * 1024 + kk + acol];
            float4 f1 = *(const float4*)&Af[(size_t)(m0 + arow) * 1024 + kk + acol + 4];
            float4 f2 = *(const float4*)&Af[(size_t)(m0 + arow) * 1024 + kk + acol + 8];
            float4 f3 = *(const float4*)&Af[(size_t)(m0 + arow) * 1024 + kk + acol + 12];
            half8 h0, h1;
            h0[0]=(half_t)f0.x; h0[1]=(half_t)f0.y; h0[2]=(half_t)f0.z; h0[3]=(half_t)f0.w;
            h0[4]=(half_t)f1.x; h0[5]=(half_t)f1.y; h0[6]=(half_t)f1.z; h0[7]=(half_t)f1.w;
            h1[0]=(half_t)f2.x; h1[1]=(half_t)f2.y; h1[2]=(half_t)f2.z; h1[3]=(half_t)f2.w;
            h1[4]=(half_t)f3.x; h1[5]=(half_t)f3.y; h1[6]=(half_t)f3.z; h1[7]=(half_t)f3.w;
            *(half8*)&As[kh][0][arow * 72 + acol] = h0;
            *(half8*)&As[kh][0][arow * 72 + acol + 8] = h1;
        } else {
            *(half8*)&As[kh][0][arow * 72 + acol]     = *(const half8*)&Ah[(size_t)(m0 + arow) * 1024 + kk + acol];
            *(half8*)&As[kh][0][arow * 72 + acol + 8] = *(const half8*)&Ah[(size_t)(m0 + arow) * 1024 + kk + acol + 8];
        }
        *(half8*)&Bs[kh][0][arow * 72 + acol]     = *(const half8*)&Bt[(size_t)(n0 + arow) * 1024 + kk + acol];
        *(half8*)&Bs[kh][0][arow * 72 + acol + 8] = *(const half8*)&Bt[(size_t)(n0 + arow) * 1024 + kk + acol + 8];
    }
    __syncthreads();

    floatx4 zero = {0.f, 0.f, 0.f, 0.f};
    floatx4 acc[2][2];
    acc[0][0] = zero; acc[0][1] = zero; acc[1][0] = zero; acc[1][1] = zero;

    float4 pf0, pf1, pf2, pf3; half8 ph0, ph1, pb0, pb1;
    for (int it = 0; it < 8; ++it) {
        if (it < 7) {
            int kk = kbase + (it + 1) * 64;
            if (Af) {
                pf0 = *(const float4*)&Af[(size_t)(m0 + arow) * 1024 + kk + acol];
                pf1 = *(const float4*)&Af[(size_t)(m0 + arow) * 1024 + kk + acol + 4];
                pf2 = *(const float4*)&Af[(size_t)(m0 + arow) * 1024 + kk + acol + 8];
                pf3 = *(const float4*)&Af[(size_t)(m0 + arow) * 1024 + kk + acol + 12];
            } else {
                ph0 = *(const half8*)&Ah[(size_t)(m0 + arow) * 1024 + kk + acol];
                ph1 = *(const half8*)&Ah[(size_t)(m0 + arow) * 1024 + kk + acol + 8];
            }
            pb0 = *(const half8*)&Bt[(size_t)(n0 + arow) * 1024 + kk + acol];
            pb1 = *(const half8*)&Bt[(size_t)(n0 + arow) * 1024 + kk + acol + 8];
        }
        const half_t* Ab = &As[kh][it & 1][0];
        const half_t* Bb = &Bs[kh][it & 1][0];
        #pragma unroll
        for (int ks = 0; ks < 2; ++ks) {
            half8 a0 = *(const half8*)&Ab[(wm * 32 + lr) * 72 + ks * 32 + quad * 8];
            half8 a1 = *(const half8*)&Ab[(wm * 32 + 16 + lr) * 72 + ks * 32 + quad * 8];
            half8 b0 = *(const half8*)&Bb[(wn * 32 + lr) * 72 + ks * 32 + quad * 8];
            half8 b1 = *(const half8*)&Bb[(wn * 32 + 16 + lr) * 72 + ks * 32 + quad * 8];
            acc[0][0] = mfma16(a0, b0, acc[0][0]);
            acc[0][1] = mfma16(a0, b1, acc[0][1]);
            acc[1][0] = mfma16(a1, b0, acc[1][0]);
            acc[1][1] = mfma16(a1, b1, acc[1][1]);
        }
        __syncthreads();
        if (it < 7) {
            int buf = (it + 1) & 1;
            if (Af) {
                half8 h0, h1;
                h0[0]=(half_t)pf0.x; h0[1]=(half_t)pf0.y; h0[2]=(half_t)pf0.z; h0[3]=(half_t)pf0.w;
                h0[4]=(half_t)pf1.x; h0[5]=(half_t)pf1.y; h0[6]=(half_t)pf1.z; h0[7]=(half_t)pf1.w;
                h1[0]=(half_t)pf2.x; h1[1]=(half_t)pf2.y; h1[2]=(half_t)pf2.z; h1[3]=(half_t)pf2.w;
                h1[4]=(half_t)pf3.x; h1[5]=(half_t)pf3.y; h1[6]=(half_t)pf3.z; h1[7]=(half_t)pf3.w;
                *(half8*)&As[kh][buf][arow * 72 + acol] = h0;
                *(half8*)&As[kh][buf][arow * 72 + acol + 8] = h1;
            } else {
                *(half8*)&As[kh][buf][arow * 72 + acol] = ph0;
                *(half8*)&As[kh][buf][arow * 72 + acol + 8] = ph1;
            }
            *(half8*)&Bs[kh][buf][arow * 72 + acol] = pb0;
            *(half8*)&Bs[kh][buf][arow * 72 + acol + 8] = pb1;
            __syncthreads();
        }
    }

    // merge K-halves (kh1 -> LDS fp32, kh0 adds)
    float* M = (float*)&Bs[0][0][0];   // 64 x 66 floats
    if (kh == 1) {
        #pragma unroll
        for (int mi = 0; mi < 2; mi++)
            #pragma unroll
            for (int ni = 0; ni < 2; ni++)
                #pragma unroll
                for (int r = 0; r < 4; r++)
                    M[(wm * 32 + mi * 16 + quad * 4 + r) * 66 + wn * 32 + ni * 16 + lr] = acc[mi][ni][r];
    }
    __syncthreads();
    if (kh == 0) {
        #pragma unroll
        for (int mi = 0; mi < 2; mi++)
            #pragma unroll
            for (int ni = 0; ni < 2; ni++)
                #pragma unroll
                for (int r = 0; r < 4; r++)
                    acc[mi][ni][r] += M[(wm * 32 + mi * 16 + quad * 4 + r) * 66 + wn * 32 + ni * 16 + lr];
    }

    if (task == 0) {
        if (kh == 0) {
            #pragma unroll
            for (int mi = 0; mi < 2; mi++)
                #pragma unroll
                for (int ni = 0; ni < 2; ni++)
                    #pragma unroll
                    for (int r = 0; r < 4; r++) {
                        int m = m0 + wm * 32 + mi * 16 + quad * 4 + r;
                        int n = n0 + wn * 32 + ni * 16 + lr;
                        qs_h[(size_t)m * 1024 + n] = (half_t)(acc[mi][ni][r] * (0.125f * LOG2E));
                    }
        }
    } else if (task == 2) {
        if (kh == 0) {
            #pragma unroll
            for (int mi = 0; mi < 2; mi++)
                #pragma unroll
                for (int ni = 0; ni < 2; ni++)
                    #pragma unroll
                    for (int r = 0; r < 4; r++) {
                        int m = m0 + wm * 32 + mi * 16 + quad * 4 + r;
                        int n = n0 + wn * 32 + ni * 16 + lr;
                        out[(size_t)m * 1024 + n] = acc[mi][ni][r];
                    }
        }
    } else {
        float* Ct = (float*)&As[0][0][0];   // 64 x 68 floats (transposed acc)
        if (kh == 0) {
            #pragma unroll
            for (int mi = 0; mi < 2; mi++)
                #pragma unroll
                for (int ni = 0; ni < 2; ni++)
                    #pragma unroll
                    for (int r = 0; r < 4; r++)
                        Ct[(wn * 32 + ni * 16 + lr) * 68 + wm * 32 + mi * 16 + quad * 4 + r] = acc[mi][ni][r];
        }
        __syncthreads();
        if (kh == 0) {
            const int b = m0 >> 9, jm0 = m0 & 511;
            if (n0 < 256) {
                int gg = n0 >> 6;
                {
                    int d = t8 >> 2, jc = (t8 & 3) * 16;
                    float4 vv[4];
                    #pragma unroll
                    for (int u = 0; u < 4; u++) vv[u] = *(float4*)&Ct[d * 68 + jc + u * 4];
                    #pragma unroll
                    for (int t = 0; t < 4; t++)
                        #pragma unroll
                        for (int u = 0; u < 4; u++)
                            *(float4*)&out_k[((size_t)((b * 16 + gg * 4 + t) * 64 + d)) * 1536 + 1024 + jm0 + jc + u * 4] = vv[u];
                }
                {
                    int j = t8 >> 2, dc = (t8 & 3) * 16;
                    half8 o0, o1;
                    #pragma unroll
                    for (int u = 0; u < 8; u++) o0[u] = (half_t)Ct[(dc + u) * 68 + j];
                    #pragma unroll
                    for (int u = 0; u < 8; u++) o1[u] = (half_t)Ct[(dc + 8 + u) * 68 + j];
                    *(half8*)&kp_h[((size_t)(b * 512 + jm0 + j)) * 256 + n0 + dc] = o0;
                    *(half8*)&kp_h[((size_t)(b * 512 + jm0 + j)) * 256 + n0 + dc + 8] = o1;
                }
            } else {
                int gg = (n0 - 256) >> 6;
                {
                    int j = t8 >> 2, dc = (t8 & 3) * 16;
                    float4 vv[4];
                    #pragma unroll
                    for (int u = 0; u < 4; u++) {
                        float4 x;
                        x.x = Ct[(dc + u * 4 + 0) * 68 + j];
                        x.y = Ct[(dc + u * 4 + 1) * 68 + j];
                        x.z = Ct[(dc + u * 4 + 2) * 68 + j];
                        x.w = Ct[(dc + u * 4 + 3) * 68 + j];
                        vv[u] = x;
                    }
                    #pragma unroll
                    for (int t = 0; t < 4; t++)
                        #pragma unroll
                        for (int u = 0; u < 4; u++)
                            *(float4*)&out_v[(((size_t)(b * 16 + gg * 4 + t) * 1536) + 1024 + jm0 + j) * 64 + dc + u * 4] = vv[u];
                }
                {   // Vp4[(b*4+gg)][jc'][d][4]
                    int d = t8 >> 2, jc16 = (t8 & 3) * 16;
                    #pragma unroll
                    for (int u = 0; u < 4; u++) {
                        half4v o;
                        #pragma unroll
                        for (int s2 = 0; s2 < 4; s2++) o[s2] = (half_t)Ct[d * 68 + jc16 + u * 4 + s2];
                        *(half4v*)&Vp4[(((size_t)(b * 4 + gg) * 128 + ((jm0 + jc16) >> 2) + u) * 64 + d) * 4] = o;
                    }
                }
            }
        }
    }
}

// ---------------------------------------------------------------------------
// Flash v8: barrier-free main loop split at the cache/projected boundary
// (jt<12 from Kc/Vc4, jt>=12 from kp_h/Vp4) so all addressing is pointer
// increments -- no per-iter 64-bit recompute or pointer selects. K and V
// prefetched one iter ahead in regs; running bias-table offset.
// 512 thr / 8 waves; wave jh owns 16 j-rows per 128-tile.
// ---------------------------------------------------------------------------
__global__ __launch_bounds__(512, 4) void flash(const half_t* __restrict__ qs_h,
                                                const half_t* __restrict__ Kc,
                                                const half_t* __restrict__ kp_h,
                                                const half_t* __restrict__ Vc4,
                                                const half_t* __restrict__ Vp4,
                                                const half_t* __restrict__ embc,
                                                half_t* __restrict__ AO)
{
    __shared__ __align__(16) unsigned char smem_raw[61824];
    half_t* bt = (half_t*)smem_raw;              // [32][210]

    const int bh = blockIdx.x, b = bh >> 4, h = bh & 15, g = h >> 2;
    const int i0 = blockIdx.y * 32;
    const int tid = threadIdx.x, jh = tid >> 6, l = tid & 63;
    const int quad = l >> 4, lr = l & 15;

    // Q frags straight from global: qf[ih][kh], row i = ih*16+lr
    half8 qf[2][2];
    #pragma unroll
    for (int ih = 0; ih < 2; ih++) {
        const half_t* qsrc = &qs_h[((size_t)(b * 512 + i0 + ih * 16 + lr)) * 1024 + h * 64];
        qf[ih][0] = *(const half8*)(qsrc + quad * 8);
        qf[ih][1] = *(const half8*)(qsrc + 32 + quad * 8);
    }

    floatx4 zero = {0.f, 0.f, 0.f, 0.f};
    {   // bias GEMM: bt[i][t-64] = q_i . embc[t]; wave -> (ih = jh&1, tk chunk)
        int ih = jh & 1;
        for (int tk = 4 + (jh >> 1); tk < 17; tk += 4) {
            floatx4 acc = zero;
            half8 e0 = *(const half8*)&embc[(size_t)(tk * 16 + lr) * 64 + quad * 8];
            half8 e1 = *(const half8*)&embc[(size_t)(tk * 16 + lr) * 64 + 32 + quad * 8];
            acc = mfma16(e0, qf[ih][0], acc);    // D[m=t][n=i]
            acc = mfma16(e1, qf[ih][1], acc);
            #pragma unroll
            for (int r = 0; r < 4; r++)
                bt[(ih * 16 + lr) * 210 + tk * 16 + quad * 4 + r - 64] = (half_t)acc[r];
        }
    }
    __syncthreads();   // bt ready

    // per-lane constants
    float bfv[2][4];
    #pragma unroll
    for (int ih = 0; ih < 2; ih++)
        #pragma unroll
        for (int r = 0; r < 4; r++) {
            int f = (lr & 7) - ((quad & 1) * 4 + r) + 7;     // 0..14
            bfv[ih][r] = (float)bt[(ih * 16 + lr) * 210 + 192 + f];
        }
    const half_t* btr0 = bt + lr * 210;
    const half_t* btr1 = bt + (16 + lr) * 210;
    // toff(jt, ih) = tof0 - jt*16 (+2 for ih=1); qtr1 = qtr0 + 2 exactly
    const int tof0 = 255 + ((i0 + lr) >> 3) - (jh * 2 + (quad >> 1));

    floatx4 accO[2][4];
    #pragma unroll
    for (int ih = 0; ih < 2; ih++)
        #pragma unroll
        for (int ni = 0; ni < 4; ni++) accO[ih][ni] = zero;
    floatx4 accS[2];
    accS[0] = zero; accS[1] = zero;
    const half4v vone = {(half_t)1.f, (half_t)1.f, (half_t)1.f, (half_t)1.f};

    // base pointers: cache phase (jt<12) and projected phase (jt>=12)
    const half_t* kcp = Kc   + ((size_t)bh * 1536 + jh * 16 + lr) * 64 + quad * 8;   // +8192/iter
    const half_t* kpp = kp_h + ((size_t)b * 512 + jh * 16 + lr) * 256 + g * 64 + quad * 8; // +32768/iter
    const half_t* vcp = Vc4  + (size_t)bh * 98304 + (jh * 4 + quad) * 256 + lr * 4;  // +8192/iter
    const half_t* vpp = Vp4  + ((size_t)(b * 4 + g)) * 32768 + (jh * 4 + quad) * 256 + lr * 4;

    half8 kc0 = *(const half8*)kcp;
    half8 kc1 = *(const half8*)(kcp + 32);
    half4v vb[4];
    #pragma unroll
    for (int ni = 0; ni < 4; ni++) vb[ni] = *(const half4v*)(vcp + ni * 64);

    auto body = [&](int tof) {
        floatx4 s[2];
        s[0] = mfma16(kc0, qf[0][0], zero);
        s[0] = mfma16(kc1, qf[0][1], s[0]);
        s[1] = mfma16(kc0, qf[1][0], zero);
        s[1] = mfma16(kc1, qf[1][1], s[1]);
        float tb0 = (float)btr0[min(tof, 190)];
        float tb1 = (float)btr1[min(tof + 2, 190)];
        #pragma unroll
        for (int r = 0; r < 4; r++) s[0][r] = exp2f(s[0][r] + tb0 + bfv[0][r]);
        #pragma unroll
        for (int r = 0; r < 4; r++) s[1][r] = exp2f(s[1][r] + tb1 + bfv[1][r]);
        #pragma unroll
        for (int ih = 0; ih < 2; ih++) {
            half4v pf;
            #pragma unroll
            for (int r = 0; r < 4; r++) pf[r] = (half_t)s[ih][r];
            accS[ih] = mfma16x16(pf, vone, accS[ih]);
            #pragma unroll
            for (int ni = 0; ni < 4; ni++)
                accO[ih][ni] = mfma16x16(pf, vb[ni], accO[ih][ni]);
        }
    };

    // phase 1: jt = 0..11 from cache (iter 11 prefetches the projected tile)
    for (int jt = 0; jt < 12; ++jt) {
        const half_t* knp = (jt < 11) ? kcp + 8192 : kpp;
        const half_t* vnp = (jt < 11) ? vcp + 8192 : vpp;
        half8 kn0 = *(const half8*)knp;
        half8 kn1 = *(const half8*)(knp + 32);
        half4v vn[4];
        #pragma unroll
        for (int ni = 0; ni < 4; ni++) vn[ni] = *(const half4v*)(vnp + ni * 64);
        body(tof0 - jt * 16);
        kc0 = kn0; kc1 = kn1;
        #pragma unroll
        for (int ni = 0; ni < 4; ni++) vb[ni] = vn[ni];
        kcp = knp; vcp = vnp;
    }
    // phase 2: jt = 12..15 from projected K/V (pointer strides 32768 / 8192)
    for (int jt = 12; jt < 16; ++jt) {
        half8 kn0, kn1; half4v vn[4];
        if (jt < 15) {
            kn0 = *(const half8*)(kcp + 32768);
            kn1 = *(const half8*)(kcp + 32768 + 32);
            #pragma unroll
            for (int ni = 0; ni < 4; ni++) vn[ni] = *(const half4v*)(vcp + 8192 + ni * 64);
        }
        body(tof0 - jt * 16);
        if (jt < 15) {
            kc0 = kn0; kc1 = kn1;
            #pragma unroll
            for (int ni = 0; ni < 4; ni++) vb[ni] = vn[ni];
            kcp += 32768; vcp += 8192;
        }
    }

    // 8-way jh merge in LDS (bt dead after this barrier)
    __syncthreads();
    float* Mf = (float*)smem_raw;          // 7 partials x 32 x 68 fp32
    float* Sf = Mf + 7 * 32 * 68;          // 7 x 32 fp32
    if (jh != 0) {
        const int p = jh - 1;
        #pragma unroll
        for (int ih = 0; ih < 2; ih++) {
            #pragma unroll
            for (int ni = 0; ni < 4; ni++)
                #pragma unroll
                for (int r = 0; r < 4; r++)
                    Mf[(p * 32 + ih * 16 + quad * 4 + r) * 68 + ni * 16 + lr] = accO[ih][ni][r];
            if (lr == 0) {
                #pragma unroll
                for (int r = 0; r < 4; r++)
                    Sf[p * 32 + ih * 16 + quad * 4 + r] = accS[ih][r];
            }
        }
    }
    __syncthreads();
    if (jh == 0) {
        #pragma unroll
        for (int ih = 0; ih < 2; ih++) {
            float inv[4];
            #pragma unroll
            for (int r = 0; r < 4; r++) {
                float t = accS[ih][r];
                #pragma unroll
                for (int p = 0; p < 7; p++) t += Sf[p * 32 + ih * 16 + quad * 4 + r];
                inv[r] = 1.0f / t;
            }
            #pragma unroll
            for (int ni = 0; ni < 4; ni++)
                #pragma unroll
                for (int r = 0; r < 4; r++) {
                    float o = accO[ih][ni][r];
                    #pragma unroll
                    for (int p = 0; p < 7; p++)
                        o += Mf[(p * 32 + ih * 16 + quad * 4 + r) * 68 + ni * 16 + lr];
                    int row = ih * 16 + quad * 4 + r;
                    AO[((size_t)(b * 512 + i0 + row)) * 1024 + h * 64 + ni * 16 + lr] =
                        (half_t)(o * inv[r]);
                }
        }
    }
}

// ---------------------------------------------------------------------------
extern "C" void kernel_launch(void* const* d_in, const int* in_sizes, int n_in,
                              void* d_out, int out_size, void* d_ws, size_t ws_size,
                              hipStream_t stream)
{
    const float* q       = (const float*)d_in[0];
    const float* k       = (const float*)d_in[1];
    const float* v       = (const float*)d_in[2];
    const float* cache_k = (const float*)d_in[3];
    const float* cache_v = (const float*)d_in[4];
    const float* Wq      = (const float*)d_in[5];
    const float* Wk      = (const float*)d_in[6];
    const float* Wv      = (const float*)d_in[7];
    const float* Wo      = (const float*)d_in[8];
    const float* emb_t   = (const float*)d_in[9];
    const float* emb_f   = (const float*)d_in[10];

    float* out   = (float*)d_out;                 // (2,512,1024)
    float* out_k = out + 1048576;                 // (32,64,1536)
    float* out_v = out_k + 3145728;               // (32,1536,64)

    half_t* ws = (half_t*)d_ws;
    half_t* qs_h = ws;                  // 1048576
    half_t* kp_h = ws + 1048576;        //  262144
    half_t* Vp4  = ws + 1310720;        //  262144  (2*4 groups)[128][64][4]
    half_t* Kc   = ws + 1572864;        // 3145728
    half_t* Vc4  = ws + 4718592;        // 3145728  [32][384][64][4]
    half_t* WqT  = ws + 7864320;        // 1048576
    half_t* WkvT = ws + 8912896;        //  524288
    half_t* WoT  = ws + 9437184;        // 1048576
    half_t* embc = ws + 10485760;       //   20480
    half_t* AO   = ws + 10506240;       // 1048576

    prep<<<dim3(24, 32, 3), 256, 0, stream>>>(cache_k, cache_v, Wq, Wk, Wv, Wo,
                                              emb_t, emb_f, Kc, Vc4, out_k, out_v,
                                              WqT, WkvT, WoT, embc);
    proj<<<dim3(384), 512, 0, stream>>>(0, q, k, v, nullptr, WqT, WkvT, WoT,
                                        qs_h, kp_h, Vp4, out, out_k, out_v);
    flash<<<dim3(32, 16), 512, 0, stream>>>(qs_h, Kc, kp_h, Vc4, Vp4, embc, AO);
    proj<<<dim3(256), 512, 0, stream>>>(1, q, k, v, AO, WqT, WkvT, WoT,
                                        qs_h, kp_h, Vp4, out, out_k, out_v);
}

// Round 7
// 167.911 us; speedup vs baseline: 2.1958x; 1.0368x over previous
//
#include <hip/hip_runtime.h>
#include <math.h>

typedef _Float16 half_t;
typedef _Float16 half8  __attribute__((ext_vector_type(8)));
typedef _Float16 half4v __attribute__((ext_vector_type(4)));
typedef float    floatx4 __attribute__((ext_vector_type(4)));

#define LOG2E 1.44269504088896f

static __device__ __forceinline__ floatx4 mfma16(half8 a, half8 b, floatx4 c) {
    return __builtin_amdgcn_mfma_f32_16x16x32_f16(a, b, c, 0, 0, 0);
}
static __device__ __forceinline__ floatx4 mfma16x16(half4v a, half4v b, floatx4 c) {
    return __builtin_amdgcn_mfma_f32_16x16x16f16(a, b, c, 0, 0, 0);
}

// ---------------------------------------------------------------------------
// prep (256 thr): z=0 cache_k -> Kc[bh][j][d] fp16 + out_k shift fp32
//                 z=1 cache_v -> VcT[bh][d][j] fp16 + out_v shift fp32
//                 z=2 weight transposes + embc build. All float4 loads.
// ---------------------------------------------------------------------------
__global__ __launch_bounds__(256) void prep(const float* __restrict__ cache_k,
                                            const float* __restrict__ cache_v,
                                            const float* __restrict__ Wq,
                                            const float* __restrict__ Wk,
                                            const float* __restrict__ Wv,
                                            const float* __restrict__ Wo,
                                            const float* __restrict__ emb_t,
                                            const float* __restrict__ emb_f,
                                            half_t* __restrict__ Kc,
                                            half_t* __restrict__ VcT,
                                            float* __restrict__ out_k,
                                            float* __restrict__ out_v,
                                            half_t* __restrict__ WqT,
                                            half_t* __restrict__ WkvT,
                                            half_t* __restrict__ WoT,
                                            half_t* __restrict__ embc)
{
    const int tid = threadIdx.x;
    const int z = blockIdx.z;
    __shared__ float t[64][65];
    if (z == 0) {
        const int bh = blockIdx.y, j0 = blockIdx.x * 64;
        const bool shift = (j0 >= 512);
        #pragma unroll
        for (int i2 = 0; i2 < 4; i2++) {
            int idx = i2 * 256 + tid;
            int d = idx >> 4, j4 = (idx & 15) * 4;
            float4 vv = *(const float4*)&cache_k[((size_t)bh * 64 + d) * 1536 + j0 + j4];
            *(float4*)&t[d][j4] = vv;
            if (shift) *(float4*)&out_k[((size_t)bh * 64 + d) * 1536 + j0 - 512 + j4] = vv;
        }
        __syncthreads();
        #pragma unroll
        for (int i2 = 0; i2 < 2; i2++) {
            int idx = i2 * 256 + tid;
            int j = idx >> 3, db = (idx & 7) * 8;
            half8 o;
            #pragma unroll
            for (int u = 0; u < 8; u++) o[u] = (half_t)t[db + u][j];
            *(half8*)&Kc[((size_t)bh * 1536 + j0 + j) * 64 + db] = o;
        }
    } else if (z == 1) {
        const int bh = blockIdx.y, j0 = blockIdx.x * 64;
        const bool shift = (j0 >= 512);
        #pragma unroll
        for (int i2 = 0; i2 < 4; i2++) {
            int idx = i2 * 256 + tid;
            int j = idx >> 4, d4 = (idx & 15) * 4;
            float4 vv = *(const float4*)&cache_v[((size_t)bh * 1536 + j0 + j) * 64 + d4];
            *(float4*)&t[j][d4] = vv;
            if (shift) *(float4*)&out_v[((size_t)bh * 1536 + j0 + j - 512) * 64 + d4] = vv;
        }
        __syncthreads();
        #pragma unroll
        for (int i2 = 0; i2 < 2; i2++) {
            int idx = i2 * 256 + tid;
            int d = idx >> 3, jb = (idx & 7) * 8;
            half8 o;
            #pragma unroll
            for (int u = 0; u < 8; u++) o[u] = (half_t)t[jb + u][d];
            *(half8*)&VcT[((size_t)bh * 64 + d) * 1536 + j0 + jb] = o;
        }
    } else {
        const int id = blockIdx.y * 24 + blockIdx.x;
        const float* src; half_t* dst; int Ncols, n0, k0;
        if (id < 256)      { src = Wq; dst = WqT; Ncols = 1024; n0 = (id & 15) * 64; k0 = (id >> 4) * 64; }
        else if (id < 320) { int q2 = id - 256; src = Wk; dst = WkvT; Ncols = 256; n0 = (q2 & 3) * 64; k0 = (q2 >> 2) * 64; }
        else if (id < 384) { int q2 = id - 320; src = Wv; dst = WkvT + 256 * 1024; Ncols = 256; n0 = (q2 & 3) * 64; k0 = (q2 >> 2) * 64; }
        else if (id < 640) { int q2 = id - 384; src = Wo; dst = WoT; Ncols = 1024; n0 = (q2 & 15) * 64; k0 = (q2 >> 4) * 64; }
        else if (id < 720) {
            int idx = (id - 640) * 256 + tid;
            int row = idx >> 6, col = idx & 63;
            float val = 0.f;
            if (row < 255) val = emb_t[row * 64 + col];
            else if (row >= 256 && row < 271) val = emb_f[(row - 256) * 64 + col];
            embc[idx] = (half_t)val;
            return;
        } else return;
        #pragma unroll
        for (int i2 = 0; i2 < 4; i2++) {
            int idx = i2 * 256 + tid;
            int r = idx >> 4, c4 = (idx & 15) * 4;
            *(float4*)&t[r][c4] = *(const float4*)&src[(size_t)(k0 + r) * Ncols + n0 + c4];
        }
        __syncthreads();
        #pragma unroll
        for (int i2 = 0; i2 < 2; i2++) {
            int idx = i2 * 256 + tid;
            int n = idx >> 3, kb = (idx & 7) * 8;
            half8 o;
            #pragma unroll
            for (int u = 0; u < 8; u++) o[u] = (half_t)t[kb + u][n];
            *(half8*)&dst[(size_t)(n0 + n) * 1024 + k0 + kb] = o;
        }
    }
}

// ---------------------------------------------------------------------------
// proj (512 thr, 8 waves, K-split): two 4-wave groups each GEMM half of K
// (BK=64 x 8 iters, double-buffered, register prefetch), fp32 LDS merge.
// phase 0: blocks 0..255 q-proj (fp16, x0.125*log2e), 256..383 k/v-proj
// (LDS-transpose epilogue). phase 1: out-proj (fp32 out).
// ---------------------------------------------------------------------------
__global__ __launch_bounds__(512) void proj(int phase,
                                            const float* __restrict__ qin,
                                            const float* __restrict__ kin,
                                            const float* __restrict__ vin,
                                            const half_t* __restrict__ AO,
                                            const half_t* __restrict__ WqT,
                                            const half_t* __restrict__ WkvT,
                                            const half_t* __restrict__ WoT,
                                            half_t* __restrict__ qs_h,
                                            half_t* __restrict__ kp_h,
                                            half_t* __restrict__ vpT,
                                            float* __restrict__ out,
                                            float* __restrict__ out_k,
                                            float* __restrict__ out_v)
{
    __shared__ __align__(16) half_t As[2][2][64 * 72];
    __shared__ __align__(16) half_t Bs[2][2][64 * 72];
    const int id = blockIdx.x;
    int task, m0, n0;
    const float* Af = nullptr; const half_t* Ah = nullptr; const half_t* Bt;
    if (phase == 1)      { task = 2; m0 = (id >> 4) * 64; n0 = (id & 15) * 64; Ah = AO; Bt = WoT; }
    else if (id < 256)   { task = 0; m0 = (id >> 4) * 64; n0 = (id & 15) * 64; Af = qin; Bt = WqT; }
    else { task = 1; int t = id - 256; m0 = (t >> 3) * 64; n0 = (t & 7) * 64;
           Af = (n0 < 256) ? kin : vin; Bt = WkvT; }

    const int tid = threadIdx.x;
    const int kh = tid >> 8, t8 = tid & 255;
    const int w4 = (tid >> 6) & 3, l = tid & 63;
    const int quad = l >> 4, lr = l & 15, wm = w4 >> 1, wn = w4 & 1;
    const int arow = t8 >> 2, acol = (t8 & 3) * 16;
    const int kbase = kh * 512;

    {   // stage tile 0
        int kk = kbase;
        if (Af) {
            float4 f0 = *(const float4*)&Af[(size_t)(m0 + arow) * 1024 + kk + acol];
            float4 f1 = *(const float4*)&Af[(size_t)(m0 + arow) * 1024 + kk + acol + 4];
            float4 f2 = *(const float4*)&Af[(size_t)(m0 + arow) * 1024 + kk + acol + 8];
            float4 f3 = *(const float4*)&Af[(size_t)(m0 + arow) * 1024 + kk + acol + 12];
            half8 h0, h1;
            h0[0]=(half_t)f0.x; h0[1]=(half_t)f0.y; h0[2]=(half_t)f0.z; h0[3]=(half_t)f0.w;
            h0[4]=(half_t)f1.x; h0[5]=(half_t)f1.y; h0[6]=(half_t)f1.z; h0[7]=(half_t)f1.w;
            h1[0]=(half_t)f2.x; h1[1]=(half_t)f2.y; h1[2]=(half_t)f2.z; h1[3]=(half_t)f2.w;
            h1[4]=(half_t)f3.x; h1[5]=(half_t)f3.y; h1[6]=(half_t)f3.z; h1[7]=(half_t)f3.w;
            *(half8*)&As[kh][0][arow * 72 + acol] = h0;
            *(half8*)&As[kh][0][arow * 72 + acol + 8] = h1;
        } else {
            *(half8*)&As[kh][0][arow * 72 + acol]     = *(const half8*)&Ah[(size_t)(m0 + arow) * 1024 + kk + acol];
            *(half8*)&As[kh][0][arow * 72 + acol + 8] = *(const half8*)&Ah[(size_t)(m0 + arow) * 1024 + kk + acol + 8];
        }
        *(half8*)&Bs[kh][0][arow * 72 + acol]     = *(const half8*)&Bt[(size_t)(n0 + arow) * 1024 + kk + acol];
        *(half8*)&Bs[kh][0][arow * 72 + acol + 8] = *(const half8*)&Bt[(size_t)(n0 + arow) * 1024 + kk + acol + 8];
    }
    __syncthreads();

    floatx4 zero = {0.f, 0.f, 0.f, 0.f};
    floatx4 acc[2][2];
    acc[0][0] = zero; acc[0][1] = zero; acc[1][0] = zero; acc[1][1] = zero;

    float4 pf0, pf1, pf2, pf3; half8 ph0, ph1, pb0, pb1;
    for (int it = 0; it < 8; ++it) {
        if (it < 7) {
            int kk = kbase + (it + 1) * 64;
            if (Af) {
                pf0 = *(const float4*)&Af[(size_t)(m0 + arow) * 1024 + kk + acol];
                pf1 = *(const float4*)&Af[(size_t)(m0 + arow) * 1024 + kk + acol + 4];
                pf2 = *(const float4*)&Af[(size_t)(m0 + arow) * 1024 + kk + acol + 8];
                pf3 = *(const float4*)&Af[(size_t)(m0 + arow) * 1024 + kk + acol + 12];
            } else {
                ph0 = *(const half8*)&Ah[(size_t)(m0 + arow) * 1024 + kk + acol];
                ph1 = *(const half8*)&Ah[(size_t)(m0 + arow) * 1024 + kk + acol + 8];
            }
            pb0 = *(const half8*)&Bt[(size_t)(n0 + arow) * 1024 + kk + acol];
            pb1 = *(const half8*)&Bt[(size_t)(n0 + arow) * 1024 + kk + acol + 8];
        }
        const half_t* Ab = &As[kh][it & 1][0];
        const half_t* Bb = &Bs[kh][it & 1][0];
        #pragma unroll
        for (int ks = 0; ks < 2; ++ks) {
            half8 a0 = *(const half8*)&Ab[(wm * 32 + lr) * 72 + ks * 32 + quad * 8];
            half8 a1 = *(const half8*)&Ab[(wm * 32 + 16 + lr) * 72 + ks * 32 + quad * 8];
            half8 b0 = *(const half8*)&Bb[(wn * 32 + lr) * 72 + ks * 32 + quad * 8];
            half8 b1 = *(const half8*)&Bb[(wn * 32 + 16 + lr) * 72 + ks * 32 + quad * 8];
            acc[0][0] = mfma16(a0, b0, acc[0][0]);
            acc[0][1] = mfma16(a0, b1, acc[0][1]);
            acc[1][0] = mfma16(a1, b0, acc[1][0]);
            acc[1][1] = mfma16(a1, b1, acc[1][1]);
        }
        __syncthreads();
        if (it < 7) {
            int buf = (it + 1) & 1;
            if (Af) {
                half8 h0, h1;
                h0[0]=(half_t)pf0.x; h0[1]=(half_t)pf0.y; h0[2]=(half_t)pf0.z; h0[3]=(half_t)pf0.w;
                h0[4]=(half_t)pf1.x; h0[5]=(half_t)pf1.y; h0[6]=(half_t)pf1.z; h0[7]=(half_t)pf1.w;
                h1[0]=(half_t)pf2.x; h1[1]=(half_t)pf2.y; h1[2]=(half_t)pf2.z; h1[3]=(half_t)pf2.w;
                h1[4]=(half_t)pf3.x; h1[5]=(half_t)pf3.y; h1[6]=(half_t)pf3.z; h1[7]=(half_t)pf3.w;
                *(half8*)&As[kh][buf][arow * 72 + acol] = h0;
                *(half8*)&As[kh][buf][arow * 72 + acol + 8] = h1;
            } else {
                *(half8*)&As[kh][buf][arow * 72 + acol] = ph0;
                *(half8*)&As[kh][buf][arow * 72 + acol + 8] = ph1;
            }
            *(half8*)&Bs[kh][buf][arow * 72 + acol] = pb0;
            *(half8*)&Bs[kh][buf][arow * 72 + acol + 8] = pb1;
            __syncthreads();
        }
    }

    // merge K-halves (kh1 -> LDS fp32, kh0 adds)
    float* M = (float*)&Bs[0][0][0];   // 64 x 66 floats
    if (kh == 1) {
        #pragma unroll
        for (int mi = 0; mi < 2; mi++)
            #pragma unroll
            for (int ni = 0; ni < 2; ni++)
                #pragma unroll
                for (int r = 0; r < 4; r++)
                    M[(wm * 32 + mi * 16 + quad * 4 + r) * 66 + wn * 32 + ni * 16 + lr] = acc[mi][ni][r];
    }
    __syncthreads();
    if (kh == 0) {
        #pragma unroll
        for (int mi = 0; mi < 2; mi++)
            #pragma unroll
            for (int ni = 0; ni < 2; ni++)
                #pragma unroll
                for (int r = 0; r < 4; r++)
                    acc[mi][ni][r] += M[(wm * 32 + mi * 16 + quad * 4 + r) * 66 + wn * 32 + ni * 16 + lr];
    }

    if (task == 0) {
        if (kh == 0) {
            #pragma unroll
            for (int mi = 0; mi < 2; mi++)
                #pragma unroll
                for (int ni = 0; ni < 2; ni++)
                    #pragma unroll
                    for (int r = 0; r < 4; r++) {
                        int m = m0 + wm * 32 + mi * 16 + quad * 4 + r;
                        int n = n0 + wn * 32 + ni * 16 + lr;
                        qs_h[(size_t)m * 1024 + n] = (half_t)(acc[mi][ni][r] * (0.125f * LOG2E));
                    }
        }
    } else if (task == 2) {
        if (kh == 0) {
            #pragma unroll
            for (int mi = 0; mi < 2; mi++)
                #pragma unroll
                for (int ni = 0; ni < 2; ni++)
                    #pragma unroll
                    for (int r = 0; r < 4; r++) {
                        int m = m0 + wm * 32 + mi * 16 + quad * 4 + r;
                        int n = n0 + wn * 32 + ni * 16 + lr;
                        out[(size_t)m * 1024 + n] = acc[mi][ni][r];
                    }
        }
    } else {
        float* Ct = (float*)&As[0][0][0];   // 64 x 68 floats (transposed acc)
        if (kh == 0) {
            #pragma unroll
            for (int mi = 0; mi < 2; mi++)
                #pragma unroll
                for (int ni = 0; ni < 2; ni++)
                    #pragma unroll
                    for (int r = 0; r < 4; r++)
                        Ct[(wn * 32 + ni * 16 + lr) * 68 + wm * 32 + mi * 16 + quad * 4 + r] = acc[mi][ni][r];
        }
        __syncthreads();
        if (kh == 0) {
            const int b = m0 >> 9, jm0 = m0 & 511;
            if (n0 < 256) {
                int gg = n0 >> 6;
                {
                    int d = t8 >> 2, jc = (t8 & 3) * 16;
                    float4 vv[4];
                    #pragma unroll
                    for (int u = 0; u < 4; u++) vv[u] = *(float4*)&Ct[d * 68 + jc + u * 4];
                    #pragma unroll
                    for (int t = 0; t < 4; t++)
                        #pragma unroll
                        for (int u = 0; u < 4; u++)
                            *(float4*)&out_k[((size_t)((b * 16 + gg * 4 + t) * 64 + d)) * 1536 + 1024 + jm0 + jc + u * 4] = vv[u];
                }
                {
                    int j = t8 >> 2, dc = (t8 & 3) * 16;
                    half8 o0, o1;
                    #pragma unroll
                    for (int u = 0; u < 8; u++) o0[u] = (half_t)Ct[(dc + u) * 68 + j];
                    #pragma unroll
                    for (int u = 0; u < 8; u++) o1[u] = (half_t)Ct[(dc + 8 + u) * 68 + j];
                    *(half8*)&kp_h[((size_t)(b * 512 + jm0 + j)) * 256 + n0 + dc] = o0;
                    *(half8*)&kp_h[((size_t)(b * 512 + jm0 + j)) * 256 + n0 + dc + 8] = o1;
                }
            } else {
                int gg = (n0 - 256) >> 6;
                {
                    int j = t8 >> 2, dc = (t8 & 3) * 16;
                    float4 vv[4];
                    #pragma unroll
                    for (int u = 0; u < 4; u++) {
                        float4 x;
                        x.x = Ct[(dc + u * 4 + 0) * 68 + j];
                        x.y = Ct[(dc + u * 4 + 1) * 68 + j];
                        x.z = Ct[(dc + u * 4 + 2) * 68 + j];
                        x.w = Ct[(dc + u * 4 + 3) * 68 + j];
                        vv[u] = x;
                    }
                    #pragma unroll
                    for (int t = 0; t < 4; t++)
                        #pragma unroll
                        for (int u = 0; u < 4; u++)
                            *(float4*)&out_v[(((size_t)(b * 16 + gg * 4 + t) * 1536) + 1024 + jm0 + j) * 64 + dc + u * 4] = vv[u];
                }
                {
                    int d = t8 >> 2, jc = (t8 & 3) * 16;
                    half8 o0, o1;
                    #pragma unroll
                    for (int u = 0; u < 8; u++) o0[u] = (half_t)Ct[d * 68 + jc + u];
                    #pragma unroll
                    for (int u = 0; u < 8; u++) o1[u] = (half_t)Ct[d * 68 + jc + 8 + u];
                    *(half8*)&vpT[((size_t)((b * 4 + gg) * 64 + d)) * 512 + jm0 + jc] = o0;
                    *(half8*)&vpT[((size_t)((b * 4 + gg) * 64 + d)) * 512 + jm0 + jc + 8] = o1;
                }
            }
        }
    }
}

// ---------------------------------------------------------------------------
// Flash v5: 512 thr / 8 waves, 32 Q-rows per block, grid (bh=32, it=16)=512
// -> 2 blocks/CU x 8 waves = 16 waves/CU. Wave (wq, jh): wq = i-half
// of 16 rows, jh = j-quarter (32 of each 128-j tile).
// LDS XOR-swizzled (16B blocks, row&7) -> conflict-free ds_read_b128/b64,
// no pads (Ks 16KB, Vs 16KB, Qs 4KB, bt 13.4KB = 50.3KB).
// Row sums via MFMA with ones-B operand; 4-way jh merge in LDS.
// ---------------------------------------------------------------------------
__global__ __launch_bounds__(512, 4) void flash(const half_t* __restrict__ qs_h,
                                                const half_t* __restrict__ Kc,
                                                const half_t* __restrict__ kp_h,
                                                const half_t* __restrict__ VcT,
                                                const half_t* __restrict__ vpT,
                                                const half_t* __restrict__ embc,
                                                half_t* __restrict__ AO)
{
    __shared__ __align__(16) half_t smem[25152];        // 50304 B
    half_t* Ks = smem;            // [128][64]  swizzled: chunk ^= row&7
    half_t* Vs = smem + 8192;     // [64][128]  (V^T [d][j]) swizzled: chunk ^= d&7
    half_t* Qs = smem + 16384;    // [32][64]   swizzled: chunk ^= row&7
    half_t* bt = smem + 18432;    // [32][210]

    const int bh = blockIdx.x, b = bh >> 4, h = bh & 15, g = h >> 2;
    const int i0 = blockIdx.y * 32;
    const int tid = threadIdx.x, w = tid >> 6, l = tid & 63;
    const int quad = l >> 4, lr = l & 15;
    const int wq = w >> 2, jh = w & 3;

    // stage Q (32 rows x 64), swizzled
    if (tid < 256) {
        int row = tid >> 3, cc = tid & 7;
        *(half8*)&Qs[row * 64 + ((cc ^ (row & 7)) * 8)] =
            *(const half8*)&qs_h[((size_t)(b * 512 + i0 + row)) * 1024 + h * 64 + cc * 8];
    }

    // preload tile-0 K/V into registers (K: 128x64, V^T: 64x128)
    half8 kr[2], vr[2];
    #pragma unroll
    for (int u = 0; u < 2; u++) {
        int row = u * 64 + (tid >> 3);
        kr[u] = *(const half8*)&Kc[((size_t)bh * 1536 + row) * 64 + (tid & 7) * 8];
        int d = u * 32 + (tid >> 4);
        vr[u] = *(const half8*)&VcT[((size_t)bh * 64 + d) * 1536 + (tid & 15) * 8];
    }
    __syncthreads();   // Qs ready

    // Q as B-operand frags (lane n = i = wq*16+lr); swizzled read
    half8 qf0 = *(const half8*)&Qs[(wq * 16 + lr) * 64 + ((quad ^ (lr & 7)) * 8)];
    half8 qf1 = *(const half8*)&Qs[(wq * 16 + lr) * 64 + (((4 + quad) ^ (lr & 7)) * 8)];

    floatx4 zero = {0.f, 0.f, 0.f, 0.f};
    // bias GEMM: bt[i][t-64] = q_i . embc[t], 13 tk-chunks split 4-way by jh
    for (int tk = 4 + jh; tk < 17; tk += 4) {
        floatx4 acc = zero;
        half8 e0 = *(const half8*)&embc[(size_t)(tk * 16 + lr) * 64 + quad * 8];
        half8 e1 = *(const half8*)&embc[(size_t)(tk * 16 + lr) * 64 + 32 + quad * 8];
        acc = mfma16(e0, qf0, acc);        // D[m=t][n=i]
        acc = mfma16(e1, qf1, acc);
        #pragma unroll
        for (int r = 0; r < 4; r++)
            bt[(wq * 16 + lr) * 210 + tk * 16 + quad * 4 + r - 64] = (half_t)acc[r];
    }

    // write tile-0 K/V to LDS (swizzled)
    #pragma unroll
    for (int u = 0; u < 2; u++) {
        int row = u * 64 + (tid >> 3);
        *(half8*)&Ks[row * 64 + (((tid & 7) ^ (row & 7)) * 8)] = kr[u];
        int d = u * 32 + (tid >> 4);
        *(half8*)&Vs[d * 128 + (((tid & 15) ^ (d & 7)) * 8)] = vr[u];
    }
    __syncthreads();   // bt + tile0 ready

    // per-thread constants: this lane owns row i = wq*16 + lr
    const int qtr = (i0 + wq * 16 + lr) >> 3;
    float bfv[4];
    #pragma unroll
    for (int r = 0; r < 4; r++) {
        int f = (lr & 7) - ((quad & 1) * 4 + r) + 7;     // 0..14
        bfv[r] = (float)bt[(wq * 16 + lr) * 210 + 192 + f];
    }

    floatx4 accO[4];
    #pragma unroll
    for (int ni = 0; ni < 4; ni++) accO[ni] = zero;
    floatx4 accS = zero;                  // row sums, rows quad*4+r (ones-B MFMA)
    const half4v vone = {(half_t)1.f, (half_t)1.f, (half_t)1.f, (half_t)1.f};

    for (int jt = 0; jt < 16; ++jt) {
        if (jt < 15) {   // prefetch next tile into registers
            const int j1 = (jt + 1) * 128;
            #pragma unroll
            for (int u = 0; u < 2; u++) {
                int row = u * 64 + (tid >> 3);
                const half_t* ksrc = (j1 < 1536)
                    ? &Kc[((size_t)bh * 1536 + j1 + row) * 64 + (tid & 7) * 8]
                    : &kp_h[((size_t)(b * 512 + j1 - 1536 + row)) * 256 + g * 64 + (tid & 7) * 8];
                kr[u] = *(const half8*)ksrc;
                int d = u * 32 + (tid >> 4);
                const half_t* vsrc = (j1 < 1536)
                    ? &VcT[((size_t)bh * 64 + d) * 1536 + j1 + (tid & 15) * 8]
                    : &vpT[((size_t)(b * 4 + g) * 64 + d) * 512 + (j1 - 1536) + (tid & 15) * 8];
                vr[u] = *(const half8*)vsrc;
            }
        }

        // S^T = K . Q^T : D[m=j][n=i], 2 chunks of 16 j (this wave's quarter)
        floatx4 s[2];
        #pragma unroll
        for (int c = 0; c < 2; c++) {
            int row = jh * 32 + c * 16 + lr;
            half8 kf0 = *(const half8*)&Ks[row * 64 + ((quad ^ (row & 7)) * 8)];
            half8 kf1 = *(const half8*)&Ks[row * 64 + (((4 + quad) ^ (row & 7)) * 8)];
            s[c] = mfma16(kf0, qf0, zero);
            s[c] = mfma16(kf1, qf1, s[c]);
        }
        // bias + exp2 (no max: scores bounded)
        const int ktb = jt * 16 + jh * 4 + (quad >> 1);
        const half_t* btrow = &bt[(wq * 16 + lr) * 210];
        #pragma unroll
        for (int c = 0; c < 2; c++) {
            int toff = 255 + qtr - (ktb + c * 2);
            toff = min(toff, 190);
            float tb = (float)btrow[toff];
            #pragma unroll
            for (int r = 0; r < 4; r++)
                s[c][r] = exp2f(s[c][r] + tb + bfv[r]);
        }
        // P regs -> A-frags (16x16x16: m=lane=i, k=quad*4+r=j) ; PV + row sums
        #pragma unroll
        for (int c = 0; c < 2; c++) {
            half4v pf;
            #pragma unroll
            for (int r = 0; r < 4; r++) pf[r] = (half_t)s[c][r];
            accS = mfma16x16(pf, vone, accS);          // D[m=i][*] = rowsum
            const int bj = jh * 4 + c * 2 + (quad >> 1);
            #pragma unroll
            for (int ni = 0; ni < 4; ni++) {
                int d = ni * 16 + lr;
                half4v vb = *(const half4v*)&Vs[d * 128 + ((bj ^ (lr & 7)) * 8) + (quad & 1) * 4];
                accO[ni] = mfma16x16(pf, vb, accO[ni]);
            }
        }
        __syncthreads();   // all waves done with Ks/Vs
        if (jt < 15) {
            #pragma unroll
            for (int u = 0; u < 2; u++) {
                int row = u * 64 + (tid >> 3);
                *(half8*)&Ks[row * 64 + (((tid & 7) ^ (row & 7)) * 8)] = kr[u];
                int d = u * 32 + (tid >> 4);
                *(half8*)&Vs[d * 128 + (((tid & 15) ^ (d & 7)) * 8)] = vr[u];
            }
            __syncthreads();
        }
    }

    // 4-way jh merge in LDS (reuse Ks/Vs region, all dead now).
    // Partials p = (jh-1)*2 + wq, each 16 rows x 68-stride fp32 + 16 sums.
    float* Mf = (float*)smem;             // 6 * 16 * 68 floats = 26112 B
    float* Sf = Mf + 6 * 16 * 68;         // 6 * 16 floats
    if (jh != 0) {
        int p = (jh - 1) * 2 + wq;
        #pragma unroll
        for (int ni = 0; ni < 4; ni++)
            #pragma unroll
            for (int r = 0; r < 4; r++)
                Mf[(p * 16 + quad * 4 + r) * 68 + ni * 16 + lr] = accO[ni][r];
        if (lr == 0) {
            #pragma unroll
            for (int r = 0; r < 4; r++)
                Sf[p * 16 + quad * 4 + r] = accS[r];
        }
    }
    __syncthreads();
    if (jh == 0) {
        float inv[4];
        #pragma unroll
        for (int r = 0; r < 4; r++) {
            float t = accS[r];
            #pragma unroll
            for (int jj = 0; jj < 3; jj++) t += Sf[(jj * 2 + wq) * 16 + quad * 4 + r];
            inv[r] = 1.0f / t;
        }
        #pragma unroll
        for (int ni = 0; ni < 4; ni++)
            #pragma unroll
            for (int r = 0; r < 4; r++) {
                float o = accO[ni][r];
                #pragma unroll
                for (int jj = 0; jj < 3; jj++)
                    o += Mf[((jj * 2 + wq) * 16 + quad * 4 + r) * 68 + ni * 16 + lr];
                int row = wq * 16 + quad * 4 + r;
                AO[((size_t)(b * 512 + i0 + row)) * 1024 + h * 64 + ni * 16 + lr] =
                    (half_t)(o * inv[r]);
            }
    }
}

// ---------------------------------------------------------------------------
extern "C" void kernel_launch(void* const* d_in, const int* in_sizes, int n_in,
                              void* d_out, int out_size, void* d_ws, size_t ws_size,
                              hipStream_t stream)
{
    const float* q       = (const float*)d_in[0];
    const float* k       = (const float*)d_in[1];
    const float* v       = (const float*)d_in[2];
    const float* cache_k = (const float*)d_in[3];
    const float* cache_v = (const float*)d_in[4];
    const float* Wq      = (const float*)d_in[5];
    const float* Wk      = (const float*)d_in[6];
    const float* Wv      = (const float*)d_in[7];
    const float* Wo      = (const float*)d_in[8];
    const float* emb_t   = (const float*)d_in[9];
    const float* emb_f   = (const float*)d_in[10];

    float* out   = (float*)d_out;                 // (2,512,1024)
    float* out_k = out + 1048576;                 // (32,64,1536)
    float* out_v = out_k + 3145728;               // (32,1536,64)

    half_t* ws = (half_t*)d_ws;
    half_t* qs_h = ws;                  // 1048576
    half_t* kp_h = ws + 1048576;        //  262144
    half_t* vpT  = ws + 1310720;        //  262144
    half_t* Kc   = ws + 1572864;        // 3145728
    half_t* VcT  = ws + 4718592;        // 3145728
    half_t* WqT  = ws + 7864320;        // 1048576
    half_t* WkvT = ws + 8912896;        //  524288
    half_t* WoT  = ws + 9437184;        // 1048576
    half_t* embc = ws + 10485760;       //   20480
    half_t* AO   = ws + 10506240;       // 1048576

    prep<<<dim3(24, 32, 3), 256, 0, stream>>>(cache_k, cache_v, Wq, Wk, Wv, Wo,
                                              emb_t, emb_f, Kc, VcT, out_k, out_v,
                                              WqT, WkvT, WoT, embc);
    proj<<<dim3(384), 512, 0, stream>>>(0, q, k, v, nullptr, WqT, WkvT, WoT,
                                        qs_h, kp_h, vpT, out, out_k, out_v);
    flash<<<dim3(32, 16), 512, 0, stream>>>(qs_h, Kc, kp_h, VcT, vpT, embc, AO);
    proj<<<dim3(256), 512, 0, stream>>>(1, q, k, v, AO, WqT, WkvT, WoT,
                                        qs_h, kp_h, vpT, out, out_k, out_v);
}